// Round 7
// baseline (287.973 us; speedup 1.0000x reference)
//
#include <hip/hip_runtime.h>

typedef unsigned short u16;
typedef unsigned int u32;
typedef __attribute__((ext_vector_type(2))) u32 u32x2;
typedef __attribute__((ext_vector_type(4))) u32 u32x4;
typedef __attribute__((ext_vector_type(8))) short bf16x8;
typedef __attribute__((ext_vector_type(4))) float f32x4;

// round-to-nearest-even fp32 -> bf16 (scalar fallback)
__device__ __forceinline__ u16 f2bf(float f) {
  u32 b = __float_as_uint(f);
  b += 0x7fffu + ((b >> 16) & 1u);
  return (u16)(b >> 16);
}

// packed fp32x2 -> bf16x2 (hardware v_cvt_pk_bf16_f32 on gfx950; RNE both ways)
__device__ __forceinline__ u32 pk2bf(float a, float b) {
#if __has_builtin(__builtin_amdgcn_cvt_pk_bf16_f32)
  return __builtin_bit_cast(u32, __builtin_amdgcn_cvt_pk_bf16_f32(a, b));
#else
  return (u32)f2bf(a) | ((u32)f2bf(b) << 16);
#endif
}

__device__ __forceinline__ bf16x8 mk_ones8() {
  u32x4 t;
  t[0] = t[1] = t[2] = t[3] = 0x3F803F80u;  // bf16 1.0 x2 per word
  return __builtin_bit_cast(bf16x8, t);
}

// 2^x via the native v_exp_f32 (which computes exp2). NOTE: __exp2f is a
// reserved glibc symbol -- do not use that name.
__device__ __forceinline__ float fexp2(float x) {
#if __has_builtin(__builtin_amdgcn_exp2f)
  return __builtin_amdgcn_exp2f(x);
#else
  return exp2f(x);
#endif
}

__device__ __forceinline__ f32x4 mfma32(bf16x8 a, bf16x8 b, f32x4 c) {
  return __builtin_amdgcn_mfma_f32_16x16x32_bf16(a, b, c, 0, 0, 0);
}

// async global->LDS, 16B/lane; LDS dst = wave-uniform base + lane*16 [m97/m104]
__device__ __forceinline__ void gload_lds16(const u16* g, u16* l) {
  __builtin_amdgcn_global_load_lds((const __attribute__((address_space(1))) void*)g,
                                   (__attribute__((address_space(3))) void*)l, 16, 0, 0);
}

// ---------------- fp32 -> bf16 convert, 3 tensors in ONE launch -------------
// regions: x 4096 blocks, W_attn 1536, W_out 512 (8 elems/thread each).
__global__ __launch_bounds__(256) void cvt_all(const float* __restrict__ x,
                                               const float* __restrict__ wa,
                                               const float* __restrict__ wo,
                                               u16* __restrict__ xb,
                                               u16* __restrict__ wab,
                                               u16* __restrict__ wob) {
  int blk = blockIdx.x;
  const float* in;
  u16* out;
  long base;
  if (blk < 4096) {
    in = x; out = xb; base = blk;
  } else if (blk < 5632) {
    in = wa; out = wab; base = blk - 4096;
  } else {
    in = wo; out = wob; base = blk - 5632;
  }
  long i = (base * 256 + threadIdx.x) * 8;
  u32 u[8];
#pragma unroll
  for (int j = 0; j < 8; j++) {
    u32 b = __float_as_uint(in[i + j]);
    u[j] = (b + 0x7fffu + ((b >> 16) & 1u)) >> 16;
  }
  u32x4 o;
  o[0] = u[0] | (u[1] << 16);
  o[1] = u[2] | (u[3] << 16);
  o[2] = u[4] | (u[5] << 16);
  o[3] = u[6] | (u[7] << 16);
  *(u32x4*)(out + i) = o;
}

// ---------------- shared GEMM core: C[128x128] = A[128xK] * B[128xK]^T ------
__device__ __forceinline__ void gemm_core_128(const u16* __restrict__ A,
                                              const u16* __restrict__ B, int K,
                                              int m0, int n0, u16* As, u16* Bs,
                                              f32x4 acc[4][4]) {
  int t = threadIdx.x;
  int lane = t & 63, w = t >> 6;
  int quad = lane >> 4, l16 = lane & 15;
  int wm = (w >> 1) * 64, wn = (w & 1) * 64;
  int lr = lane >> 3, lc = lane & 7;  // staging: lane -> (row-in-8, chunk slot)
  int cg = lc ^ lr;                   // swizzled global source chunk
  int swz = l16 & 7;
  for (int k0 = 0; k0 < K; k0 += 64) {
#pragma unroll
    for (int i = 0; i < 4; i++) {
      int r0 = i * 32 + w * 8;
      gload_lds16(&A[(long)(m0 + r0 + lr) * K + k0 + cg * 8], &As[r0 * 64]);
      gload_lds16(&B[(long)(n0 + r0 + lr) * K + k0 + cg * 8], &Bs[r0 * 64]);
    }
    __syncthreads();
#pragma unroll
    for (int ks = 0; ks < 2; ks++) {
      bf16x8 a[4], b[4];
#pragma unroll
      for (int tm = 0; tm < 4; tm++)
        a[tm] = *(const bf16x8*)&As[(wm + tm * 16 + l16) * 64 + ((ks * 4 + quad) ^ swz) * 8];
#pragma unroll
      for (int tn = 0; tn < 4; tn++)
        b[tn] = *(const bf16x8*)&Bs[(wn + tn * 16 + l16) * 64 + ((ks * 4 + quad) ^ swz) * 8];
#pragma unroll
      for (int tm = 0; tm < 4; tm++)
#pragma unroll
        for (int tn = 0; tn < 4; tn++)
          acc[tm][tn] = __builtin_amdgcn_mfma_f32_16x16x32_bf16(a[tm], b[tn],
                                                                acc[tm][tn], 0, 0, 0);
    }
    __syncthreads();
  }
}

// ---------------- GEMM1: kqv = x @ W_attn^T + b_attn, scattered to K/Q/Vt ---
#define QSCALE 0.1803368801f
__global__ __launch_bounds__(256) void gemm_qkv(const u16* __restrict__ A,
                                                const u16* __restrict__ B,
                                                const float* __restrict__ bias,
                                                u16* __restrict__ Kg,
                                                u16* __restrict__ Qg,
                                                u16* __restrict__ Vg) {
  __shared__ __align__(16) u16 As[128 * 64];
  __shared__ __align__(16) u16 Bs[128 * 64];
  const int K = 1024;
  int m0 = blockIdx.y * 128, n0 = blockIdx.x * 128;
  f32x4 acc[4][4];
#pragma unroll
  for (int i = 0; i < 4; i++)
#pragma unroll
    for (int j = 0; j < 4; j++) acc[i][j] = (f32x4)0.0f;
  gemm_core_128(A, B, K, m0, n0, As, Bs, acc);

  int t = threadIdx.x, lane = t & 63, w = t >> 6;
  int quad = lane >> 4, l16 = lane & 15;
  int wm = (w >> 1) * 64, wn = (w & 1) * 64;
#pragma unroll
  for (int tn = 0; tn < 4; tn++) {
    int n = n0 + wn + tn * 16 + l16;
    float bv = bias[n];
    int which = n >> 10;
    int h = (n >> 6) & 15, d = n & 63;
#pragma unroll
    for (int tm = 0; tm < 4; tm++) {
      int m = m0 + wm + tm * 16 + quad * 4;
      int b = m >> 11, s = m & 2047;
      long bh = (long)b * 16 + h;
      if (which == 2) {
        // V: 4 consecutive s -> one b64 store
        u32x2 pk;
        pk[0] = pk2bf(acc[tm][tn][0] + bv, acc[tm][tn][1] + bv);
        pk[1] = pk2bf(acc[tm][tn][2] + bv, acc[tm][tn][3] + bv);
        *(u32x2*)&Vg[(bh * 64 + d) * 2048 + s] = pk;
      } else {
#pragma unroll
        for (int r = 0; r < 4; r++) {
          float v = acc[tm][tn][r] + bv;
          if (which == 0)
            Kg[(bh * 2048 + s + r) * 64 + d] = f2bf(v);
          else
            Qg[(bh * 2048 + s + r) * 64 + d] = f2bf(v * QSCALE);
        }
      }
    }
  }
}

// ---------------- GEMM2: out = y @ W_out^T + b_out (fp32 out) ---------------
__global__ __launch_bounds__(256) void gemm_out(const u16* __restrict__ A,
                                                const u16* __restrict__ B,
                                                const float* __restrict__ bias,
                                                float* __restrict__ out) {
  __shared__ __align__(16) u16 As[128 * 64];
  __shared__ __align__(16) u16 Bs[128 * 64];
  const int K = 1024, N = 1024;
  int m0 = blockIdx.y * 128, n0 = blockIdx.x * 128;
  f32x4 acc[4][4];
#pragma unroll
  for (int i = 0; i < 4; i++)
#pragma unroll
    for (int j = 0; j < 4; j++) acc[i][j] = (f32x4)0.0f;
  gemm_core_128(A, B, K, m0, n0, As, Bs, acc);

  int t = threadIdx.x, lane = t & 63, w = t >> 6;
  int quad = lane >> 4, l16 = lane & 15;
  int wm = (w >> 1) * 64, wn = (w & 1) * 64;
#pragma unroll
  for (int tn = 0; tn < 4; tn++) {
    int n = n0 + wn + tn * 16 + l16;
    float bv = bias[n];
#pragma unroll
    for (int tm = 0; tm < 4; tm++) {
#pragma unroll
      for (int r = 0; r < 4; r++) {
        int m = m0 + wm + tm * 16 + quad * 4 + r;
        out[(long)m * N + n] = acc[tm][tn][r] + bv;
      }
    }
  }
}

// ---------------- flash attention: kv-split wave pairs, R4 P-swizzle --------
// R6 (resubmit; last round's failure was an infra flake -- container died
// twice with no compile/correctness signal; kernel re-audited: no barrier
// divergence, no OOB, P pair-sharing race-free since bit3(phys) = bit3(l16)
// ^ kvh keeps the waves' granule sets disjoint per row).
// R5's regression was EXACTLY the P bank conflicts (8.41M cyc / 1024 SIMD /
// 2.4GHz = 13.7us = the 104->117 delta). Cause: P rows shrank to 64B stride
// so the granule XOR key dropped to 3 bits (l16&7); bit3 of l16 re-aliased ->
// 4-way conflict on every P write+read. Fix: pair-SHARED P rows [32 q][64 kv]
// (128B stride), wave kvh owns granules kvh*8..+7. Logical 8B granule
// g = kvh*8 + tn*4 + quad, physical = g ^ l16 (full 4-bit key) -- per
// instruction this is const^l16 within each 16-lane phase -> 16 distinct
// bank-pairs, bank-identical to R4's measured-zero pattern, writes and reads.
// Geometry unchanged from R5: 256 thr (2 pairs), 64 q/block, grid (32,64),
// LDS 40KB -> 4 blocks/CU; per-wave kv-half work; end cross-pair reduction.
#define SYNC                                       \
  __builtin_amdgcn_sched_barrier(0);               \
  asm volatile("s_waitcnt vmcnt(0)" ::: "memory"); \
  __builtin_amdgcn_s_barrier();                    \
  __builtin_amdgcn_sched_barrier(0)

#define STAGE_KV(tt, bb)                                                       \
  do {                                                                         \
    gload_lds16(Kst + (long)(tt)*4096, Ks0 + (bb)*4096 + w * 1024);            \
    gload_lds16(Kst + (long)(tt)*4096 + 512, Ks0 + (bb)*4096 + w * 1024 + 512);\
    gload_lds16(Vst + (tt)*64, Vs0 + (bb)*4096 + w * 1024);                    \
    gload_lds16(Vst + (tt)*64 + 8 * 2048, Vs0 + (bb)*4096 + w * 1024 + 512);   \
  } while (0)

#define COMPUTE(bb)                                                            \
  do {                                                                         \
    bf16x8 kf_[2][2];                                                          \
    _Pragma("unroll") for (int tn = 0; tn < 2; tn++) {                         \
      kf_[tn][0] = *(const bf16x8*)(kL0 + (bb)*4096 + tn * 1024);              \
      kf_[tn][1] = *(const bf16x8*)(kL1 + (bb)*4096 + tn * 1024);              \
    }                                                                          \
    bf16x8 pf_[2];                                                             \
    _Pragma("unroll") for (int tq = 0; tq < 2; tq++) {                         \
      f32x4 s_[2];                                                             \
      __builtin_amdgcn_s_setprio(1);                                           \
      _Pragma("unroll") for (int tn = 0; tn < 2; tn++) {                       \
        s_[tn] = mfma32(kf_[tn][0], qf[tq][0], Z);                             \
        s_[tn] = mfma32(kf_[tn][1], qf[tq][1], s_[tn]);                        \
      }                                                                        \
      __builtin_amdgcn_s_setprio(0);                                           \
      _Pragma("unroll") for (int tn = 0; tn < 2; tn++) {                       \
        float e0 = fexp2(s_[tn][0]);                                           \
        float e1 = fexp2(s_[tn][1]);                                           \
        float e2 = fexp2(s_[tn][2]);                                           \
        float e3 = fexp2(s_[tn][3]);                                           \
        u32x2 pk;                                                              \
        pk[0] = pk2bf(e0, e1);                                                 \
        pk[1] = pk2bf(e2, e3);                                                 \
        *(u32x2*)(pW + tq * 1024 + woff[tn]) = pk;                             \
      }                                                                        \
    }                                                                          \
    _Pragma("unroll") for (int tq = 0; tq < 2; tq++) {                         \
      u32x2 lo = *(const u32x2*)(pR + tq * 1024 + prlo);                       \
      u32x2 hi = *(const u32x2*)(pR + tq * 1024 + prhi);                       \
      u32x4 cc;                                                                \
      cc[0] = lo[0];                                                           \
      cc[1] = lo[1];                                                           \
      cc[2] = hi[0];                                                           \
      cc[3] = hi[1];                                                           \
      pf_[tq] = __builtin_bit_cast(bf16x8, cc);                                \
    }                                                                          \
    __builtin_amdgcn_s_setprio(1);                                             \
    acc_sum[0] = mfma32(ONES, pf_[0], acc_sum[0]);                             \
    acc_sum[1] = mfma32(ONES, pf_[1], acc_sum[1]);                             \
    _Pragma("unroll") for (int dt = 0; dt < 4; dt++) {                         \
      bf16x8 vf = *(const bf16x8*)(vL + (bb)*4096 + dt * 1024);                \
      acc[dt][0] = mfma32(vf, pf_[0], acc[dt][0]);                             \
      acc[dt][1] = mfma32(vf, pf_[1], acc[dt][1]);                             \
    }                                                                          \
    __builtin_amdgcn_s_setprio(0);                                             \
  } while (0)

__global__ __launch_bounds__(256, 4) void attn_kernel(const u16* __restrict__ Qg,
                                                      const u16* __restrict__ Kg,
                                                      const u16* __restrict__ Vg,
                                                      u16* __restrict__ Y) {
  // one LDS block, carved: Ks 2x8KB | Vs 2x8KB | Ps 2 pairs x 4KB = 40960 B
  __shared__ __align__(16) u16 lds[20480];
  u16* Ks0 = lds;          // [buf][kv][d] chunk-swizzled
  u16* Vs0 = lds + 8192;   // [buf][d][kv] chunk-swizzled
  u16* Ps0 = lds + 16384;  // per-PAIR [32 q][64 kv], 8B granule ^ l16 (4-bit)

  int t = threadIdx.x, lane = t & 63, w = t >> 6;  // 4 waves
  int quad = lane >> 4, l16 = lane & 15;
  int p = w >> 1, kvh = w & 1;  // pair id, kv-half
  int bh = blockIdx.y;
  int q0 = blockIdx.x * 64 + p * 32;
  int lr = lane >> 3, lc = lane & 7, cg = lc ^ lr;
  int swz = l16 & 7;

  // Q fragments (MFMA B-operand), loaded once: qf[tq][ks]
  bf16x8 qf[2][2];
#pragma unroll
  for (int tq = 0; tq < 2; tq++) {
    const u16* qp = Qg + ((long)bh * 2048 + q0 + tq * 16 + l16) * 64;
    qf[tq][0] = *(const bf16x8*)(qp + quad * 8);
    qf[tq][1] = *(const bf16x8*)(qp + 32 + quad * 8);
  }

  const f32x4 Z = {0.0f, 0.0f, 0.0f, 0.0f};  // hoisted zero C-operand
  const bf16x8 ONES = mk_ones8();            // bf16 1.0 x8 (denominator MFMA)

  f32x4 acc[4][2];   // [dt d][tq q]  out^T: row=d, col=q (this wave: kv-half)
  f32x4 acc_sum[2];  // softmax denominator (this kv-half)
#pragma unroll
  for (int dt = 0; dt < 4; dt++)
#pragma unroll
    for (int tq = 0; tq < 2; tq++) acc[dt][tq] = (f32x4)0.0f;
  acc_sum[0] = (f32x4)0.0f;
  acc_sum[1] = (f32x4)0.0f;

  // loop-invariant LDS lane pointers; kf rows kvh*32 + tn*16 + l16
  const u16* kL0 = Ks0 + (kvh * 32 + l16) * 64 + (quad ^ swz) * 8;
  const u16* kL1 = Ks0 + (kvh * 32 + l16) * 64 + ((4 + quad) ^ swz) * 8;
  // vf rows dt*16+l16, kv-chunk kvh
  const u16* vL = Vs0 + l16 * 64 + ((kvh * 4 + quad) ^ swz) * 8;
  // P: pair-shared [32 q][64 kv] row (128B); granule g = kvh*8+tn*4+quad,
  // phys = g ^ l16 (full 4-bit key = R4's measured-zero pattern)
  u16* pW = Ps0 + p * 2048 + l16 * 64;
  const u16* pR = pW;
  int woff[2];
#pragma unroll
  for (int tn = 0; tn < 2; tn++) woff[tn] = ((kvh * 8 + tn * 4 + quad) ^ l16) * 4;
  int prlo = ((kvh * 8 + quad * 2) ^ l16) * 4;
  int prhi = ((kvh * 8 + quad * 2 + 1) ^ l16) * 4;

  // staging: wave w stages rows w*16+lr and w*16+8+lr of each 64-row tile
  const u16* Kst = Kg + ((long)bh * 2048 + w * 16 + lr) * 64 + cg * 8;   // +tt*4096
  const u16* Vst = Vg + ((long)(bh * 64 + w * 16 + lr)) * 2048 + cg * 8; // +tt*64

  STAGE_KV(0, 0);
  for (int tt = 0; tt < 30; tt += 2) {
    SYNC;
    STAGE_KV(tt + 1, 1);
    COMPUTE(0);
    SYNC;
    STAGE_KV(tt + 2, 0);
    COMPUTE(1);
  }
  SYNC;
  STAGE_KV(31, 1);
  COMPUTE(0);
  SYNC;
  COMPUTE(1);

  // ---- cross-pair reduction: odd wave dumps acc + denom, even wave sums ----
  __syncthreads();  // all K/V/P reads done; LDS reusable as fp32 scratch
  float* red = (float*)lds;
  int slot = (p * 64 + lane) * 44;  // stride 44 fp32 (16B-aligned, 2-way banks)
  if (kvh) {
#pragma unroll
    for (int dt = 0; dt < 4; dt++)
#pragma unroll
      for (int tq = 0; tq < 2; tq++)
        *(f32x4*)(red + slot + (dt * 2 + tq) * 4) = acc[dt][tq];
    red[slot + 32] = acc_sum[0][0];
    red[slot + 33] = acc_sum[1][0];
  }
  __syncthreads();
  if (!kvh) {
    float s0 = acc_sum[0][0] + red[slot + 32];
    float s1 = acc_sum[1][0] + red[slot + 33];
    float inv[2] = {1.0f / s0, 1.0f / s1};
    int b = bh >> 4, h = bh & 15;
#pragma unroll
    for (int tq = 0; tq < 2; tq++) {
      long row = (long)b * 2048 + q0 + tq * 16 + l16;
#pragma unroll
      for (int dt = 0; dt < 4; dt++) {
        f32x4 a = acc[dt][tq] + *(const f32x4*)(red + slot + (dt * 2 + tq) * 4);
        u32x2 pk;
        pk[0] = pk2bf(a[0] * inv[tq], a[1] * inv[tq]);
        pk[1] = pk2bf(a[2] * inv[tq], a[3] * inv[tq]);
        *(u32x2*)&Y[row * 1024 + h * 64 + dt * 16 + quad * 4] = pk;
      }
    }
  }
}

// ---------------- launch ----------------------------------------------------
extern "C" void kernel_launch(void* const* d_in, const int* in_sizes, int n_in,
                              void* d_out, int out_size, void* d_ws, size_t ws_size,
                              hipStream_t stream) {
  const float* x = (const float*)d_in[0];       // (4,2048,1024)
  const float* W_attn = (const float*)d_in[1];  // (3072,1024)
  const float* b_attn = (const float*)d_in[2];  // (3072,)
  const float* W_out = (const float*)d_in[3];   // (1024,1024)
  const float* b_out = (const float*)d_in[4];   // (1024,)
  float* out = (float*)d_out;                   // (4,2048,1024) fp32

  char* ws = (char*)d_ws;
  u16* xb = (u16*)ws;                             // 8192*1024 bf16 = 16 MB
  u16* Wab = (u16*)(ws + 16777216);               // 3072*1024 = 6 MB
  u16* Wob = (u16*)(ws + 16777216 + 6291456);     // 1024*1024 = 2 MB
  u16* Kg = (u16*)(ws + 25165824);                // (b,h,s,d) 16 MB
  u16* Qg = Kg + 8388608;                         // (b,h,s,d) pre-scaled 16 MB
  u16* Vg = Qg + 8388608;                         // (b,h,d,s) 16 MB
  u16* Yb = xb;  // alias: x no longer needed after GEMM1

  cvt_all<<<6144, 256, 0, stream>>>(x, W_attn, W_out, xb, Wab, Wob);

  gemm_qkv<<<dim3(24, 64), 256, 0, stream>>>(xb, Wab, b_attn, Kg, Qg, Vg);
  attn_kernel<<<dim3(32, 64), 256, 0, stream>>>(Qg, Kg, Vg, Yb);
  gemm_out<<<dim3(8, 64), 256, 0, stream>>>(Yb, Wob, b_out, out);
}

// Round 8
// 278.265 us; speedup vs baseline: 1.0349x; 1.0349x over previous
//
#include <hip/hip_runtime.h>

typedef unsigned short u16;
typedef unsigned int u32;
typedef __attribute__((ext_vector_type(2))) u32 u32x2;
typedef __attribute__((ext_vector_type(4))) u32 u32x4;
typedef __attribute__((ext_vector_type(8))) short bf16x8;
typedef __attribute__((ext_vector_type(4))) float f32x4;

// round-to-nearest-even fp32 -> bf16 (scalar fallback)
__device__ __forceinline__ u16 f2bf(float f) {
  u32 b = __float_as_uint(f);
  b += 0x7fffu + ((b >> 16) & 1u);
  return (u16)(b >> 16);
}

// packed fp32x2 -> bf16x2 (hardware v_cvt_pk_bf16_f32 on gfx950; RNE both ways)
__device__ __forceinline__ u32 pk2bf(float a, float b) {
#if __has_builtin(__builtin_amdgcn_cvt_pk_bf16_f32)
  return __builtin_bit_cast(u32, __builtin_amdgcn_cvt_pk_bf16_f32(a, b));
#else
  return (u32)f2bf(a) | ((u32)f2bf(b) << 16);
#endif
}

__device__ __forceinline__ bf16x8 mk_ones8() {
  u32x4 t;
  t[0] = t[1] = t[2] = t[3] = 0x3F803F80u;  // bf16 1.0 x2 per word
  return __builtin_bit_cast(bf16x8, t);
}

// 2^x via the native v_exp_f32 (which computes exp2). NOTE: __exp2f is a
// reserved glibc symbol -- do not use that name.
__device__ __forceinline__ float fexp2(float x) {
#if __has_builtin(__builtin_amdgcn_exp2f)
  return __builtin_amdgcn_exp2f(x);
#else
  return exp2f(x);
#endif
}

// async global->LDS, 16B/lane; LDS dst = wave-uniform base + lane*16 [m97/m104]
__device__ __forceinline__ void gload_lds16(const u16* g, u16* l) {
  __builtin_amdgcn_global_load_lds((const __attribute__((address_space(1))) void*)g,
                                   (__attribute__((address_space(3))) void*)l, 16, 0, 0);
}

// ---------------- fp32 -> bf16 convert, 3 tensors in ONE launch -------------
// regions: x 4096 blocks, W_attn 1536, W_out 512 (8 elems/thread each).
__global__ __launch_bounds__(256) void cvt_all(const float* __restrict__ x,
                                               const float* __restrict__ wa,
                                               const float* __restrict__ wo,
                                               u16* __restrict__ xb,
                                               u16* __restrict__ wab,
                                               u16* __restrict__ wob) {
  int blk = blockIdx.x;
  const float* in;
  u16* out;
  long base;
  if (blk < 4096) {
    in = x; out = xb; base = blk;
  } else if (blk < 5632) {
    in = wa; out = wab; base = blk - 4096;
  } else {
    in = wo; out = wob; base = blk - 5632;
  }
  long i = (base * 256 + threadIdx.x) * 8;
  u32 u[8];
#pragma unroll
  for (int j = 0; j < 8; j++) {
    u32 b = __float_as_uint(in[i + j]);
    u[j] = (b + 0x7fffu + ((b >> 16) & 1u)) >> 16;
  }
  u32x4 o;
  o[0] = u[0] | (u[1] << 16);
  o[1] = u[2] | (u[3] << 16);
  o[2] = u[4] | (u[5] << 16);
  o[3] = u[6] | (u[7] << 16);
  *(u32x4*)(out + i) = o;
}

// ---------------- shared GEMM core: C[128x128] = A[128xK] * B[128xK]^T ------
// acc[tm][tn] reg r: row m = m0+wm+tm*16+quad*4+r, col n = n0+wn+tn*16+l16.
__device__ __forceinline__ void gemm_core_128(const u16* __restrict__ A,
                                              const u16* __restrict__ B, int K,
                                              int m0, int n0, u16* As, u16* Bs,
                                              f32x4 acc[4][4]) {
  int t = threadIdx.x;
  int lane = t & 63, w = t >> 6;
  int quad = lane >> 4, l16 = lane & 15;
  int wm = (w >> 1) * 64, wn = (w & 1) * 64;
  int lr = lane >> 3, lc = lane & 7;  // staging: lane -> (row-in-8, chunk slot)
  int cg = lc ^ lr;                   // swizzled global source chunk
  int swz = l16 & 7;
  for (int k0 = 0; k0 < K; k0 += 64) {
#pragma unroll
    for (int i = 0; i < 4; i++) {
      int r0 = i * 32 + w * 8;
      gload_lds16(&A[(long)(m0 + r0 + lr) * K + k0 + cg * 8], &As[r0 * 64]);
      gload_lds16(&B[(long)(n0 + r0 + lr) * K + k0 + cg * 8], &Bs[r0 * 64]);
    }
    __syncthreads();
#pragma unroll
    for (int ks = 0; ks < 2; ks++) {
      bf16x8 a[4], b[4];
#pragma unroll
      for (int tm = 0; tm < 4; tm++)
        a[tm] = *(const bf16x8*)&As[(wm + tm * 16 + l16) * 64 + ((ks * 4 + quad) ^ swz) * 8];
#pragma unroll
      for (int tn = 0; tn < 4; tn++)
        b[tn] = *(const bf16x8*)&Bs[(wn + tn * 16 + l16) * 64 + ((ks * 4 + quad) ^ swz) * 8];
#pragma unroll
      for (int tm = 0; tm < 4; tm++)
#pragma unroll
        for (int tn = 0; tn < 4; tn++)
          acc[tm][tn] = __builtin_amdgcn_mfma_f32_16x16x32_bf16(a[tm], b[tn],
                                                                acc[tm][tn], 0, 0, 0);
    }
    __syncthreads();
  }
}

// ---------------- GEMM1 (SWAPPED): kqv^T = W_attn @ x^T, scatter K/Q/Vt -----
// R8: operands swapped so the FEATURE dim lives in the register (r) axis.
// acc reg r = feature e = m0+wm+tm*16+quad*4+r; lane l16 = token. K and Q
// stores become one u32x2 (4 consecutive d) per fragment instead of 4 scalar
// f2bf stores (4x fewer store+cvt instrs); bias becomes a f32x4 vector load;
// the which(K/Q/V) branch is BLOCK-uniform (m0>>10). V keeps scalar stores
// (d is strided in its (b,h,d,s) layout) -- 1/3 scalar vs 2/3 before.
// Output tensors/layouts unchanged: Kg (b,h,s,d), Qg scaled, Vg (b,h,d,s).
#define QSCALE 0.1803368801f
__global__ __launch_bounds__(256) void gemm_qkv(const u16* __restrict__ A,
                                                const u16* __restrict__ B,
                                                const float* __restrict__ bias,
                                                u16* __restrict__ Kg,
                                                u16* __restrict__ Qg,
                                                u16* __restrict__ Vg) {
  __shared__ __align__(16) u16 As[128 * 64];
  __shared__ __align__(16) u16 Bs[128 * 64];
  const int K = 1024;
  int m0 = blockIdx.y * 128, n0 = blockIdx.x * 128;  // m=feature, n=token
  f32x4 acc[4][4];
#pragma unroll
  for (int i = 0; i < 4; i++)
#pragma unroll
    for (int j = 0; j < 4; j++) acc[i][j] = (f32x4)0.0f;
  gemm_core_128(A, B, K, m0, n0, As, Bs, acc);

  int t = threadIdx.x, lane = t & 63, w = t >> 6;
  int quad = lane >> 4, l16 = lane & 15;
  int wm = (w >> 1) * 64, wn = (w & 1) * 64;
  int which = m0 >> 10;  // 0=K,1=Q,2=V -- uniform for the whole block
#pragma unroll
  for (int tm = 0; tm < 4; tm++) {
    int m = m0 + wm + tm * 16 + quad * 4;  // feature e (r spans m..m+3)
    int h = (m >> 6) & 15, d0 = m & 63;    // d0 = tm*16+quad*4
    f32x4 b4 = *(const f32x4*)&bias[m];
#pragma unroll
    for (int tn = 0; tn < 4; tn++) {
      int n = n0 + wn + tn * 16 + l16;  // token
      int b = n >> 11, s = n & 2047;
      long bh = (long)b * 16 + h;
      if (which == 0) {
        u32x2 pk;
        pk[0] = pk2bf(acc[tm][tn][0] + b4[0], acc[tm][tn][1] + b4[1]);
        pk[1] = pk2bf(acc[tm][tn][2] + b4[2], acc[tm][tn][3] + b4[3]);
        *(u32x2*)&Kg[(bh * 2048 + s) * 64 + d0] = pk;
      } else if (which == 1) {
        u32x2 pk;
        pk[0] = pk2bf((acc[tm][tn][0] + b4[0]) * QSCALE,
                      (acc[tm][tn][1] + b4[1]) * QSCALE);
        pk[1] = pk2bf((acc[tm][tn][2] + b4[2]) * QSCALE,
                      (acc[tm][tn][3] + b4[3]) * QSCALE);
        *(u32x2*)&Qg[(bh * 2048 + s) * 64 + d0] = pk;
      } else {
#pragma unroll
        for (int r = 0; r < 4; r++)
          Vg[(bh * 64 + d0 + r) * 2048 + s] = f2bf(acc[tm][tn][r] + b4[r]);
      }
    }
  }
}

// ---------------- GEMM2 (SWAPPED): out^T = W_out @ y^T (fp32 out) -----------
// Same swap: feature in regs -> out[(token)*1024 + feature] is a contiguous
// f32x4 store per fragment (16 b128 stores vs 64 scalar f32 before).
__global__ __launch_bounds__(256) void gemm_out(const u16* __restrict__ A,
                                                const u16* __restrict__ B,
                                                const float* __restrict__ bias,
                                                float* __restrict__ out) {
  __shared__ __align__(16) u16 As[128 * 64];
  __shared__ __align__(16) u16 Bs[128 * 64];
  const int K = 1024;
  int m0 = blockIdx.y * 128, n0 = blockIdx.x * 128;  // m=feature, n=token
  f32x4 acc[4][4];
#pragma unroll
  for (int i = 0; i < 4; i++)
#pragma unroll
    for (int j = 0; j < 4; j++) acc[i][j] = (f32x4)0.0f;
  gemm_core_128(A, B, K, m0, n0, As, Bs, acc);

  int t = threadIdx.x, lane = t & 63, w = t >> 6;
  int quad = lane >> 4, l16 = lane & 15;
  int wm = (w >> 1) * 64, wn = (w & 1) * 64;
#pragma unroll
  for (int tm = 0; tm < 4; tm++) {
    int m = m0 + wm + tm * 16 + quad * 4;  // feature
    f32x4 b4 = *(const f32x4*)&bias[m];
#pragma unroll
    for (int tn = 0; tn < 4; tn++) {
      int n = n0 + wn + tn * 16 + l16;  // token
      f32x4 o = acc[tm][tn] + b4;
      *(f32x4*)&out[(long)n * 1024 + m] = o;
    }
  }
}

// ---------------- flash attention (R4 revert: 8 waves, full-64kv/wave) ------
// R8: kv-split reverted. R7 proved the split at zero conflicts is ~5us WORSE
// than R4: same 32 tile-visits/wave but 2x waves -> per-visit fixed costs
// (SYNC, stage, barrier, loop) duplicated. This is R4 verbatim: 104us, 0
// bank conflicts, VGPR 64. 512 thr (8 waves x 32 q), grid (8,64) = exactly
// 2 blocks/CU (64KB LDS). P through pair... per-wave LDS scratch with FULL
// 4-bit granule XOR (phys = g ^ l16) -> conflict-free writes AND reads.
// 28 MFMA/visit (8 QK K=32 + 16 PV K=32 + 4 ones-denominator).
#define SYNC                                       \
  __builtin_amdgcn_sched_barrier(0);               \
  asm volatile("s_waitcnt vmcnt(0)" ::: "memory"); \
  __builtin_amdgcn_s_barrier();                    \
  __builtin_amdgcn_sched_barrier(0)

#define STAGE_KV(tt, bb)                                      \
  do {                                                        \
    gload_lds16(Kst + (long)(tt)*4096, &Ks[bb][w * 8 * 64]);  \
    gload_lds16(Vst + (tt)*64, &Vs[bb][w * 8 * 64]);          \
  } while (0)

#define COMPUTE(bb)                                                            \
  do {                                                                         \
    bf16x8 pf_[2][2];                                                          \
    _Pragma("unroll") for (int tq = 0; tq < 2; tq++) {                         \
      f32x4 s_[4];                                                             \
      __builtin_amdgcn_s_setprio(1);                                           \
      _Pragma("unroll") for (int tn = 0; tn < 4; tn++) {                       \
        bf16x8 kf0 = *(const bf16x8*)(kL0 + (bb)*4096 + tn * 1024);            \
        bf16x8 kf1 = *(const bf16x8*)(kL1 + (bb)*4096 + tn * 1024);            \
        s_[tn] = __builtin_amdgcn_mfma_f32_16x16x32_bf16(kf0, qf[tq][0], Z,    \
                                                         0, 0, 0);             \
        s_[tn] = __builtin_amdgcn_mfma_f32_16x16x32_bf16(kf1, qf[tq][1],       \
                                                         s_[tn], 0, 0, 0);     \
      }                                                                        \
      __builtin_amdgcn_s_setprio(0);                                           \
      _Pragma("unroll") for (int tn = 0; tn < 4; tn++) {                       \
        float e0 = fexp2(s_[tn][0]);                                           \
        float e1 = fexp2(s_[tn][1]);                                           \
        float e2 = fexp2(s_[tn][2]);                                           \
        float e3 = fexp2(s_[tn][3]);                                           \
        u32x2 pk;                                                              \
        pk[0] = pk2bf(e0, e1);                                                 \
        pk[1] = pk2bf(e2, e3);                                                 \
        *(u32x2*)(pW + tq * 1024 + woff[tn]) = pk;                             \
      }                                                                        \
    }                                                                          \
    _Pragma("unroll") for (int ks = 0; ks < 2; ks++)                           \
        _Pragma("unroll") for (int tq = 0; tq < 2; tq++) {                     \
      u32x2 lo = *(const u32x2*)(pR + tq * 1024 + prlo[ks]);                   \
      u32x2 hi = *(const u32x2*)(pR + tq * 1024 + prhi[ks]);                   \
      u32x4 cc;                                                                \
      cc[0] = lo[0];                                                           \
      cc[1] = lo[1];                                                           \
      cc[2] = hi[0];                                                           \
      cc[3] = hi[1];                                                           \
      pf_[tq][ks] = __builtin_bit_cast(bf16x8, cc);                            \
    }                                                                          \
    __builtin_amdgcn_s_setprio(1);                                             \
    _Pragma("unroll") for (int ks = 0; ks < 2; ks++) {                         \
      acc_sum[0] = __builtin_amdgcn_mfma_f32_16x16x32_bf16(ONES, pf_[0][ks],   \
                                                           acc_sum[0], 0, 0, 0); \
      acc_sum[1] = __builtin_amdgcn_mfma_f32_16x16x32_bf16(ONES, pf_[1][ks],   \
                                                           acc_sum[1], 0, 0, 0); \
      _Pragma("unroll") for (int dt = 0; dt < 4; dt++) {                       \
        bf16x8 vf = *(const bf16x8*)(vL[ks] + (bb)*4096 + dt * 1024);          \
        acc[dt][0] = __builtin_amdgcn_mfma_f32_16x16x32_bf16(vf, pf_[0][ks],   \
                                                             acc[dt][0], 0, 0, 0); \
        acc[dt][1] = __builtin_amdgcn_mfma_f32_16x16x32_bf16(vf, pf_[1][ks],   \
                                                             acc[dt][1], 0, 0, 0); \
      }                                                                        \
    }                                                                          \
    __builtin_amdgcn_s_setprio(0);                                             \
  } while (0)

__global__ __launch_bounds__(512, 4) void attn_kernel(const u16* __restrict__ Qg,
                                                      const u16* __restrict__ Kg,
                                                      const u16* __restrict__ Vg,
                                                      u16* __restrict__ Y) {
  __shared__ __align__(16) u16 Ks[2][64 * 64];     // [buf][kv][d] XOR-swizzled
  __shared__ __align__(16) u16 Vs[2][64 * 64];     // [buf][d][kv] XOR-swizzled
  __shared__ __align__(16) u16 Ps[8 * 32 * 64];    // per-wave [q][kv] granule-swz
  int t = threadIdx.x, lane = t & 63, w = t >> 6;  // 8 waves
  int quad = lane >> 4, l16 = lane & 15;
  int bh = blockIdx.y;
  int q0 = blockIdx.x * 256 + w * 32;
  int lr = lane >> 3, lc = lane & 7, cg = lc ^ lr;
  int swz = l16 & 7;
  u16* Pw = Ps + w * 2048;

  // Q fragments (MFMA B-operand), loaded once: qf[tq][ks]
  bf16x8 qf[2][2];
#pragma unroll
  for (int tq = 0; tq < 2; tq++) {
    const u16* qp = Qg + ((long)bh * 2048 + q0 + tq * 16 + l16) * 64;
    qf[tq][0] = *(const bf16x8*)(qp + quad * 8);
    qf[tq][1] = *(const bf16x8*)(qp + 32 + quad * 8);
  }

  const f32x4 Z = {0.0f, 0.0f, 0.0f, 0.0f};  // hoisted zero C-operand
  const bf16x8 ONES = mk_ones8();            // bf16 1.0 x8 (denominator MFMA)

  f32x4 acc[4][2];   // [dt d][tq q]  out^T: row=d, col=q
  f32x4 acc_sum[2];  // softmax denominators via ones-MFMA (all rows equal)
#pragma unroll
  for (int dt = 0; dt < 4; dt++)
#pragma unroll
    for (int tq = 0; tq < 2; tq++) acc[dt][tq] = (f32x4)0.0f;
  acc_sum[0] = (f32x4)0.0f;
  acc_sum[1] = (f32x4)0.0f;

  // loop-invariant LDS lane pointers (compile-time immediates added per use)
  const u16* kL0 = &Ks[0][l16 * 64 + (quad ^ swz) * 8];        // ks=0 chunk
  const u16* kL1 = &Ks[0][l16 * 64 + ((4 + quad) ^ swz) * 8];  // ks=1 chunk
  const u16* vL[2] = {&Vs[0][l16 * 64 + (quad ^ swz) * 8],
                      &Vs[0][l16 * 64 + ((4 + quad) ^ swz) * 8]};
  u16* pW = Pw + l16 * 64;
  const u16* pR = Pw + l16 * 64;
  // P granule swizzle: 8B granule g_phys = g_log ^ l16 (full 4-bit row key)
  int woff[4], prlo[2], prhi[2];
#pragma unroll
  for (int tn = 0; tn < 4; tn++) woff[tn] = ((tn * 4 + quad) ^ l16) * 4;
#pragma unroll
  for (int ks = 0; ks < 2; ks++) {
    prlo[ks] = ((ks * 8 + quad * 2) ^ l16) * 4;
    prhi[ks] = ((ks * 8 + quad * 2 + 1) ^ l16) * 4;
  }

  // staging base pointers: wave w stages rows w*8..w*8+7 of each tile
  const u16* Kst = Kg + ((long)bh * 2048 + w * 8 + lr) * 64 + cg * 8;   // +tt*4096
  const u16* Vst = Vg + ((long)(bh * 64 + w * 8 + lr)) * 2048 + cg * 8; // +tt*64

  STAGE_KV(0, 0);
  for (int tt = 0; tt < 30; tt += 2) {
    SYNC;
    STAGE_KV(tt + 1, 1);
    COMPUTE(0);
    SYNC;
    STAGE_KV(tt + 2, 0);
    COMPUTE(1);
  }
  SYNC;
  STAGE_KV(31, 1);
  COMPUTE(0);
  SYNC;
  COMPUTE(1);

  // epilogue: out^T row=d=dt*16+quad*4+r, col=q=tq*16+l16.
  // acc_sum rows all identical (ones-A) => full denominator in every reg.
  int b = bh >> 4, h = bh & 15;
#pragma unroll
  for (int tq = 0; tq < 2; tq++) {
    float inv = 1.0f / acc_sum[tq][0];
    long row = (long)b * 2048 + q0 + tq * 16 + l16;
#pragma unroll
    for (int dt = 0; dt < 4; dt++) {
      u32x2 pk;
      pk[0] = pk2bf(acc[dt][tq][0] * inv, acc[dt][tq][1] * inv);
      pk[1] = pk2bf(acc[dt][tq][2] * inv, acc[dt][tq][3] * inv);
      *(u32x2*)&Y[row * 1024 + h * 64 + dt * 16 + quad * 4] = pk;
    }
  }
}

// ---------------- launch ----------------------------------------------------
extern "C" void kernel_launch(void* const* d_in, const int* in_sizes, int n_in,
                              void* d_out, int out_size, void* d_ws, size_t ws_size,
                              hipStream_t stream) {
  const float* x = (const float*)d_in[0];       // (4,2048,1024)
  const float* W_attn = (const float*)d_in[1];  // (3072,1024)
  const float* b_attn = (const float*)d_in[2];  // (3072,)
  const float* W_out = (const float*)d_in[3];   // (1024,1024)
  const float* b_out = (const float*)d_in[4];   // (1024,)
  float* out = (float*)d_out;                   // (4,2048,1024) fp32

  char* ws = (char*)d_ws;
  u16* xb = (u16*)ws;                             // 8192*1024 bf16 = 16 MB
  u16* Wab = (u16*)(ws + 16777216);               // 3072*1024 = 6 MB
  u16* Wob = (u16*)(ws + 16777216 + 6291456);     // 1024*1024 = 2 MB
  u16* Kg = (u16*)(ws + 25165824);                // (b,h,s,d) 16 MB
  u16* Qg = Kg + 8388608;                         // (b,h,s,d) pre-scaled 16 MB
  u16* Vg = Qg + 8388608;                         // (b,h,d,s) 16 MB
  u16* Yb = xb;  // alias: x no longer needed after GEMM1

  cvt_all<<<6144, 256, 0, stream>>>(x, W_attn, W_out, xb, Wab, Wob);

  // SWAPPED gemms: A = weights (feature rows), B = activations (token rows)
  gemm_qkv<<<dim3(64, 24), 256, 0, stream>>>(Wab, xb, b_attn, Kg, Qg, Vg);
  attn_kernel<<<dim3(8, 64), 512, 0, stream>>>(Qg, Kg, Vg, Yb);
  gemm_out<<<dim3(64, 8), 256, 0, stream>>>(Wob, Yb, b_out, out);
}